// Round 1
// baseline (975.229 us; speedup 1.0000x reference)
//
#include <hip/hip_runtime.h>
#include <hip/hip_bf16.h>
#include <cstdint>

#define BDIM 32
#define CDIM 2048
#define HIN 14
#define N2 784      // 28*28
#define W2 28
#define KDIM 113
#define KC 112
#define NCLS 200

// ---------------- K0: concept squared norms ----------------
__global__ void k_csq(const float* __restrict__ concepts, float* __restrict__ csq) {
  int k = blockIdx.x;
  int l = threadIdx.x;
  const float* row = concepts + (size_t)k * CDIM;
  float s = 0.f;
  for (int c = l; c < CDIM; c += 64) { float v = row[c]; s += v * v; }
#pragma unroll
  for (int off = 32; off > 0; off >>= 1) s += __shfl_down(s, off, 64);
  if (l == 0) csq[k] = s;
}

// ---------------- K3: fused upsample + dist GEMM + softmax + logit partials ----------------
#define BM 128
#define BN 128
#define BC 32
#define LDA 132
#define LDB 132
#define NTH 512

__global__ __launch_bounds__(NTH) void k_main(
    const float* __restrict__ x,         // [32][2048][14][14]
    const float* __restrict__ concepts,  // [113][2048]
    const float* __restrict__ cfcw,      // [2048]
    const float* __restrict__ csq,       // [113]
    float* __restrict__ attn_out,        // [32][113][784]
    float* __restrict__ part)            // [32][7][112]
{
  __shared__ union alignas(16) U {
    struct {
      float As[BC][LDA];
      float Bs[BC][LDB];
      float red[4][BN][2];
    } s;
    float Sm[KDIM][LDB];
  } u;
  __shared__ float xsq_s[BN], proj_s[BN], csq_s[BM];

  const int tid = threadIdx.x;
  const int b = blockIdx.y;
  const int bx = blockIdx.x;
  const int n0 = bx * BN;
  const int ty = tid >> 4;   // 0..31 -> rows ty*4..ty*4+3
  const int tx = tid & 15;   // 0..15 -> cols tx*8..tx*8+7
  const int g = tid >> 7;    // 0..3
  const int nn = tid & 127;  // staged column (fixed per thread)

  // Bilinear coefficients for column nn (computed once).
  // src = (o+0.5)*0.5 - 0.5 = 0.5*o - 0.25, edge-clamped (== jax.image.resize / F.interpolate acf)
  int n = n0 + nn;
  bool nvalid = n < N2;
  int i2 = n / W2; if (i2 > 27) i2 = 27;
  int j2 = n % W2;
  float si = 0.5f * i2 - 0.25f;
  float sj = 0.5f * j2 - 0.25f;
  float fif = floorf(si), fjf = floorf(sj);
  int ii = (int)fif, jj = (int)fjf;
  float fi = si - fif, fj = sj - fjf;
  int ia = ii < 0 ? 0 : ii;
  int ib = (ii + 1 > 13) ? 13 : (ii + 1);
  int ja = jj < 0 ? 0 : jj;
  int jb = (jj + 1 > 13) ? 13 : (jj + 1);
  float w00 = (1.f - fi) * (1.f - fj), w01 = (1.f - fi) * fj;
  float w10 = fi * (1.f - fj),         w11 = fi * fj;
  if (!nvalid) { w00 = w01 = w10 = w11 = 0.f; }
  const int o00 = ia * HIN + ja, o01 = ia * HIN + jb;
  const int o10 = ib * HIN + ja, o11 = ib * HIN + jb;

  float acc[4][8];
#pragma unroll
  for (int r = 0; r < 4; ++r)
#pragma unroll
    for (int s2 = 0; s2 < 8; ++s2) acc[r][s2] = 0.f;
  float psq = 0.f, ppj = 0.f;

  const float* xb = x + (size_t)b * CDIM * (HIN * HIN);

  for (int c0 = 0; c0 < CDIM; c0 += BC) {
    // stage A (concepts): coalesced 32-float segments, rows >=113 zero-padded
#pragma unroll
    for (int j = 0; j < (BM * BC / NTH); ++j) {
      int i = tid + j * NTH;
      int k = i >> 5, cc = i & 31;
      u.s.As[cc][k] = (k < KDIM) ? concepts[(size_t)k * CDIM + c0 + cc] : 0.f;
    }
    // stage B: on-the-fly bilinear upsample, channel cc = g + 4j, column nn
#pragma unroll
    for (int j = 0; j < 8; ++j) {
      const float* xr = xb + (size_t)(c0 + g + 4 * j) * (HIN * HIN);
      float v = w00 * xr[o00] + w01 * xr[o01] + w10 * xr[o10] + w11 * xr[o11];
      u.s.Bs[g + 4 * j][nn] = v;
    }
    __syncthreads();
    // x_sq / proj partials (rows g*8..g*8+7 of this chunk)
#pragma unroll
    for (int j = 0; j < 8; ++j) {
      float v = u.s.Bs[g * 8 + j][nn];
      psq += v * v;
      ppj = fmaf(v, cfcw[c0 + g * 8 + j], ppj);
    }
    // GEMM: 32 FMA per c-iter per thread, float4 LDS reads
#pragma unroll
    for (int cc = 0; cc < BC; ++cc) {
      float a4[4], b8[8];
      *(float4*)a4 = *(const float4*)&u.s.As[cc][ty * 4];
      *(float4*)&b8[0] = *(const float4*)&u.s.Bs[cc][tx * 8];
      *(float4*)&b8[4] = *(const float4*)&u.s.Bs[cc][tx * 8 + 4];
#pragma unroll
      for (int r = 0; r < 4; ++r)
#pragma unroll
        for (int s2 = 0; s2 < 8; ++s2)
          acc[r][s2] = fmaf(a4[r], b8[s2], acc[r][s2]);
    }
    __syncthreads();
  }

  // reduce x_sq / proj across the 4 cc-groups
  u.s.red[g][nn][0] = psq;
  u.s.red[g][nn][1] = ppj;
  if (tid < KDIM) csq_s[tid] = csq[tid];
  __syncthreads();
  if (tid < BN) {
    float s = 0.f, p = 0.f;
#pragma unroll
    for (int gg = 0; gg < 4; ++gg) { s += u.s.red[gg][tid][0]; p += u.s.red[gg][tid][1]; }
    xsq_s[tid] = s; proj_s[tid] = p;
  }
  __syncthreads();

  // dists -> Sm (negated, ready for softmax)
#pragma unroll
  for (int r = 0; r < 4; ++r) {
    int k = ty * 4 + r;
    if (k < KDIM) {
#pragma unroll
      for (int s2 = 0; s2 < 8; ++s2) {
        int col = tx * 8 + s2;
        float d2 = csq_s[k] + xsq_s[col] - 2.f * acc[r][s2];
        u.Sm[k][col] = -sqrtf(fmaxf(d2, 0.f));
      }
    }
  }
  __syncthreads();

  // softmax over k per column; write attn (coalesced per k-row)
  if (tid < BN && (n0 + tid) < N2) {
    int col = tid;
    float m = -1e30f;
    for (int k = 0; k < KDIM; ++k) m = fmaxf(m, u.Sm[k][col]);
    float sum = 0.f;
    for (int k = 0; k < KDIM; ++k) {
      float e = __expf(u.Sm[k][col] - m);
      u.Sm[k][col] = e;
      sum += e;
    }
    float rinv = 1.f / sum;
    float* op = attn_out + (size_t)b * KDIM * N2 + n0 + col;
    for (int k = 0; k < KDIM; ++k) {
      float a = u.Sm[k][col] * rinv;
      u.Sm[k][col] = a;
      op[(size_t)k * N2] = a;
    }
  }
  __syncthreads();

  // logit partials: logits[b,k] += sum_n attn[k,n]*proj[n]  (k < 112 only)
  if (tid < KC) {
    int nmax = N2 - n0; if (nmax > BN) nmax = BN;
    float lg = 0.f;
    for (int c2 = 0; c2 < nmax; ++c2) lg = fmaf(u.Sm[tid][c2], proj_s[c2], lg);
    part[((size_t)b * 7 + bx) * KC + tid] = lg;
  }
}

// ---------------- K4: reduce partials -> sigmoid -> concept_scores ----------------
__global__ void k_sig(const float* __restrict__ part, const float* __restrict__ cfcb,
                      float* __restrict__ cs_out) {
  int i = blockIdx.x * blockDim.x + threadIdx.x;
  if (i >= BDIM * KC) return;
  int b = i / KC, k = i % KC;
  float l = cfcb[0];
#pragma unroll
  for (int t = 0; t < 7; ++t) l += part[((size_t)b * 7 + t) * KC + k];
  cs_out[i] = 1.f / (1.f + __expf(-l));
}

// ---------------- K5: preds = (cs @ concepts[:-1]) @ labw^T + labb ----------------
__global__ __launch_bounds__(256) void k_preds(
    const float* __restrict__ concepts, const float* __restrict__ labw,
    const float* __restrict__ labb, const float* __restrict__ cs,
    float* __restrict__ preds) {
  __shared__ float cs_s[KC];
  __shared__ float tmp[CDIM];
  int b = blockIdx.x, tid = threadIdx.x;
  if (tid < KC) cs_s[tid] = cs[b * KC + tid];
  __syncthreads();
  for (int c = tid; c < CDIM; c += 256) {
    float a = 0.f;
    for (int k = 0; k < KC; ++k) a = fmaf(cs_s[k], concepts[(size_t)k * CDIM + c], a);
    tmp[c] = a;
  }
  __syncthreads();
  int w = tid >> 6, lane = tid & 63;
  for (int cls = w; cls < NCLS; cls += 4) {
    const float* wr = labw + (size_t)cls * CDIM;
    float a = 0.f;
    for (int c = lane; c < CDIM; c += 64) a = fmaf(tmp[c], wr[c], a);
#pragma unroll
    for (int off = 32; off > 0; off >>= 1) a += __shfl_down(a, off, 64);
    if (lane == 0) preds[b * NCLS + cls] = a + labb[cls];
  }
}

extern "C" void kernel_launch(void* const* d_in, const int* in_sizes, int n_in,
                              void* d_out, int out_size, void* d_ws, size_t ws_size,
                              hipStream_t stream) {
  const float* x        = (const float*)d_in[0];
  const float* concepts = (const float*)d_in[1];
  const float* cfcw     = (const float*)d_in[2];
  const float* cfcb     = (const float*)d_in[3];
  const float* labw     = (const float*)d_in[4];
  const float* labb     = (const float*)d_in[5];

  float* out    = (float*)d_out;
  float* sm_out = out;                                  // [32][113][784]
  float* cs_out = out + (size_t)BDIM * KDIM * N2;       // [32][112]
  float* pr_out = cs_out + (size_t)BDIM * KC;           // [32][200]

  float* csq  = (float*)d_ws;       // 113 floats (pad to 128)
  float* part = csq + 128;          // 32*7*112 floats

  k_csq <<<dim3(KDIM), dim3(64), 0, stream>>>(concepts, csq);
  k_main<<<dim3(7, BDIM), dim3(NTH), 0, stream>>>(x, concepts, cfcw, csq, sm_out, part);
  k_sig <<<dim3((BDIM * KC + 255) / 256), dim3(256), 0, stream>>>(part, cfcb, cs_out);
  k_preds<<<dim3(BDIM), dim3(256), 0, stream>>>(concepts, labw, labb, cs_out, pr_out);
}

// Round 2
// 310.019 us; speedup vs baseline: 3.1457x; 3.1457x over previous
//
#include <hip/hip_runtime.h>
#include <hip/hip_bf16.h>
#include <cstdint>

#define BDIM 32
#define CDIM 2048
#define HIN 14
#define N2 784      // 28*28
#define W2 28
#define KDIM 113
#define KC 112
#define NCLS 200

// ---------------- K0: concept squared norms ----------------
__global__ void k_csq(const float* __restrict__ concepts, float* __restrict__ csq) {
  int k = blockIdx.x;
  int l = threadIdx.x;
  const float* row = concepts + (size_t)k * CDIM;
  float s = 0.f;
  for (int c = l; c < CDIM; c += 64) { float v = row[c]; s += v * v; }
#pragma unroll
  for (int off = 32; off > 0; off >>= 1) s += __shfl_down(s, off, 64);
  if (l == 0) csq[k] = s;
}

// ---------------- K3: fused upsample + dist GEMM + softmax + logit partials ----------------
#define BM 128
#define BN 128
#define BC 32
#define LDA 132
#define LDB 132
#define NTH 512

__global__ __launch_bounds__(NTH) void k_main(
    const float* __restrict__ x,         // [32][2048][14][14]
    const float* __restrict__ concepts,  // [113][2048]
    const float* __restrict__ cfcw,      // [2048]
    const float* __restrict__ csq,       // [113]
    float* __restrict__ attn_out,        // [32][113][784]
    float* __restrict__ part)            // [32][7][112]
{
  __shared__ union alignas(16) U {
    struct {
      float As[BC][LDA];
      float Bs[BC][LDB];
      float red[4][BN][2];
    } s;
    float Sm[KDIM][LDB];
  } u;
  __shared__ float xsq_s[BN], proj_s[BN], csq_s[BM];

  const int tid = threadIdx.x;
  const int b = blockIdx.y;
  const int bx = blockIdx.x;
  const int n0 = bx * BN;
  const int ty = tid >> 4;   // 0..31 -> rows ty*4..ty*4+3
  const int tx = tid & 15;   // 0..15 -> cols tx*8..tx*8+7
  const int g = tid >> 7;    // 0..3
  const int nn = tid & 127;  // staged column (fixed per thread)

  // Bilinear coefficients for column nn (computed once).
  // src = (o+0.5)*0.5 - 0.5 = 0.5*o - 0.25, edge-clamped (== jax.image.resize / F.interpolate acf)
  int n = n0 + nn;
  bool nvalid = n < N2;
  int i2 = n / W2; if (i2 > 27) i2 = 27;
  int j2 = n % W2;
  float si = 0.5f * i2 - 0.25f;
  float sj = 0.5f * j2 - 0.25f;
  float fif = floorf(si), fjf = floorf(sj);
  int ii = (int)fif, jj = (int)fjf;
  float fi = si - fif, fj = sj - fjf;
  int ia = ii < 0 ? 0 : ii;
  int ib = (ii + 1 > 13) ? 13 : (ii + 1);
  int ja = jj < 0 ? 0 : jj;
  int jb = (jj + 1 > 13) ? 13 : (jj + 1);
  float w00 = (1.f - fi) * (1.f - fj), w01 = (1.f - fi) * fj;
  float w10 = fi * (1.f - fj),         w11 = fi * fj;
  if (!nvalid) { w00 = w01 = w10 = w11 = 0.f; }
  const int o00 = ia * HIN + ja, o01 = ia * HIN + jb;
  const int o10 = ib * HIN + ja, o11 = ib * HIN + jb;

  float acc[4][8];
#pragma unroll
  for (int r = 0; r < 4; ++r)
#pragma unroll
    for (int s2 = 0; s2 < 8; ++s2) acc[r][s2] = 0.f;
  float psq = 0.f, ppj = 0.f;

  const float* xb = x + (size_t)b * CDIM * (HIN * HIN);

  for (int c0 = 0; c0 < CDIM; c0 += BC) {
    // stage A (concepts): coalesced 32-float segments, rows >=113 zero-padded
#pragma unroll
    for (int j = 0; j < (BM * BC / NTH); ++j) {
      int i = tid + j * NTH;
      int k = i >> 5, cc = i & 31;
      u.s.As[cc][k] = (k < KDIM) ? concepts[(size_t)k * CDIM + c0 + cc] : 0.f;
    }
    // stage B: on-the-fly bilinear upsample, channel cc = g + 4j, column nn
#pragma unroll
    for (int j = 0; j < 8; ++j) {
      const float* xr = xb + (size_t)(c0 + g + 4 * j) * (HIN * HIN);
      float v = w00 * xr[o00] + w01 * xr[o01] + w10 * xr[o10] + w11 * xr[o11];
      u.s.Bs[g + 4 * j][nn] = v;
    }
    __syncthreads();
    // x_sq / proj partials (rows g*8..g*8+7 of this chunk)
#pragma unroll
    for (int j = 0; j < 8; ++j) {
      float v = u.s.Bs[g * 8 + j][nn];
      psq += v * v;
      ppj = fmaf(v, cfcw[c0 + g * 8 + j], ppj);
    }
    // GEMM: 32 FMA per c-iter per thread, float4 LDS reads
#pragma unroll
    for (int cc = 0; cc < BC; ++cc) {
      float a4[4], b8[8];
      *(float4*)a4 = *(const float4*)&u.s.As[cc][ty * 4];
      *(float4*)&b8[0] = *(const float4*)&u.s.Bs[cc][tx * 8];
      *(float4*)&b8[4] = *(const float4*)&u.s.Bs[cc][tx * 8 + 4];
#pragma unroll
      for (int r = 0; r < 4; ++r)
#pragma unroll
        for (int s2 = 0; s2 < 8; ++s2)
          acc[r][s2] = fmaf(a4[r], b8[s2], acc[r][s2]);
    }
    __syncthreads();
  }

  // reduce x_sq / proj across the 4 cc-groups
  u.s.red[g][nn][0] = psq;
  u.s.red[g][nn][1] = ppj;
  if (tid < KDIM) csq_s[tid] = csq[tid];
  __syncthreads();
  if (tid < BN) {
    float s = 0.f, p = 0.f;
#pragma unroll
    for (int gg = 0; gg < 4; ++gg) { s += u.s.red[gg][tid][0]; p += u.s.red[gg][tid][1]; }
    xsq_s[tid] = s; proj_s[tid] = p;
  }
  __syncthreads();

  // dists -> Sm (negated, ready for softmax)
#pragma unroll
  for (int r = 0; r < 4; ++r) {
    int k = ty * 4 + r;
    if (k < KDIM) {
#pragma unroll
      for (int s2 = 0; s2 < 8; ++s2) {
        int col = tx * 8 + s2;
        float d2 = csq_s[k] + xsq_s[col] - 2.f * acc[r][s2];
        u.Sm[k][col] = -sqrtf(fmaxf(d2, 0.f));
      }
    }
  }
  __syncthreads();

  // softmax over k per column; write attn (coalesced per k-row)
  if (tid < BN && (n0 + tid) < N2) {
    int col = tid;
    float m = -1e30f;
    for (int k = 0; k < KDIM; ++k) m = fmaxf(m, u.Sm[k][col]);
    float sum = 0.f;
    for (int k = 0; k < KDIM; ++k) {
      float e = __expf(u.Sm[k][col] - m);
      u.Sm[k][col] = e;
      sum += e;
    }
    float rinv = 1.f / sum;
    float* op = attn_out + (size_t)b * KDIM * N2 + n0 + col;
    for (int k = 0; k < KDIM; ++k) {
      float a = u.Sm[k][col] * rinv;
      u.Sm[k][col] = a;
      op[(size_t)k * N2] = a;
    }
  }
  __syncthreads();

  // logit partials: logits[b,k] += sum_n attn[k,n]*proj[n]  (k < 112 only)
  if (tid < KC) {
    int nmax = N2 - n0; if (nmax > BN) nmax = BN;
    float lg = 0.f;
    for (int c2 = 0; c2 < nmax; ++c2) lg = fmaf(u.Sm[tid][c2], proj_s[c2], lg);
    part[((size_t)b * 7 + bx) * KC + tid] = lg;
  }
}

// ---------------- K4: reduce partials -> sigmoid -> concept_scores ----------------
__global__ void k_sig(const float* __restrict__ part, const float* __restrict__ cfcb,
                      float* __restrict__ cs_out) {
  int i = blockIdx.x * blockDim.x + threadIdx.x;
  if (i >= BDIM * KC) return;
  int b = i / KC, k = i % KC;
  float l = cfcb[0];
#pragma unroll
  for (int t = 0; t < 7; ++t) l += part[((size_t)b * 7 + t) * KC + k];
  cs_out[i] = 1.f / (1.f + __expf(-l));
}

// ---------------- K5a: tmp[b,c] = sum_k cs[b,k] * concepts[k,c] ----------------
__global__ __launch_bounds__(256) void k_tmp(
    const float* __restrict__ concepts, const float* __restrict__ cs,
    float* __restrict__ tmp) {
  __shared__ float cs_s[KC];
  const int b = blockIdx.y;
  const int c = blockIdx.x * 256 + threadIdx.x;
  if (threadIdx.x < KC) cs_s[threadIdx.x] = cs[b * KC + threadIdx.x];
  __syncthreads();
  float a = 0.f;
#pragma unroll 8
  for (int k = 0; k < KC; ++k) a = fmaf(cs_s[k], concepts[(size_t)k * CDIM + c], a);
  tmp[(size_t)b * CDIM + c] = a;
}

// ---------------- K5b: preds[b,cls] = tmp[b,:].labw[cls,:] + labb ----------------
__global__ __launch_bounds__(256) void k_pred2(
    const float* __restrict__ labw, const float* __restrict__ labb,
    const float* __restrict__ tmp, float* __restrict__ preds) {
  const int w = blockIdx.x * 4 + (threadIdx.x >> 6);
  const int lane = threadIdx.x & 63;
  const int b = w / NCLS, cls = w % NCLS;
  if (b >= BDIM) return;
  const float* tr = tmp + (size_t)b * CDIM;
  const float* wr = labw + (size_t)cls * CDIM;
  float a = 0.f;
#pragma unroll
  for (int c0 = 0; c0 < CDIM; c0 += 256) {
    float4 t = *(const float4*)&tr[c0 + lane * 4];
    float4 v = *(const float4*)&wr[c0 + lane * 4];
    a += t.x * v.x + t.y * v.y + t.z * v.z + t.w * v.w;
  }
#pragma unroll
  for (int off = 32; off > 0; off >>= 1) a += __shfl_down(a, off, 64);
  if (lane == 0) preds[b * NCLS + cls] = a + labb[cls];
}

extern "C" void kernel_launch(void* const* d_in, const int* in_sizes, int n_in,
                              void* d_out, int out_size, void* d_ws, size_t ws_size,
                              hipStream_t stream) {
  const float* x        = (const float*)d_in[0];
  const float* concepts = (const float*)d_in[1];
  const float* cfcw     = (const float*)d_in[2];
  const float* cfcb     = (const float*)d_in[3];
  const float* labw     = (const float*)d_in[4];
  const float* labb     = (const float*)d_in[5];

  float* out    = (float*)d_out;
  float* sm_out = out;                                  // [32][113][784]
  float* cs_out = out + (size_t)BDIM * KDIM * N2;       // [32][112]
  float* pr_out = cs_out + (size_t)BDIM * KC;           // [32][200]

  float* csq  = (float*)d_ws;       // 113 floats (pad to 128)
  float* part = csq + 128;          // 32*7*112 floats
  float* tmp  = part + (size_t)BDIM * 7 * KC;  // 32*2048 floats

  k_csq <<<dim3(KDIM), dim3(64), 0, stream>>>(concepts, csq);
  k_main<<<dim3(7, BDIM), dim3(NTH), 0, stream>>>(x, concepts, cfcw, csq, sm_out, part);
  k_sig <<<dim3((BDIM * KC + 255) / 256), dim3(256), 0, stream>>>(part, cfcb, cs_out);
  k_tmp <<<dim3(CDIM / 256, BDIM), dim3(256), 0, stream>>>(concepts, cs_out, tmp);
  k_pred2<<<dim3((BDIM * NCLS + 3) / 4), dim3(256), 0, stream>>>(labw, labb, tmp, pr_out);
}

// Round 3
// 211.054 us; speedup vs baseline: 4.6208x; 1.4689x over previous
//
#include <hip/hip_runtime.h>
#include <hip/hip_bf16.h>
#include <cstdint>

typedef __attribute__((ext_vector_type(8))) short short8;
typedef __attribute__((ext_vector_type(4))) float f32x4;

#define BDIM 32
#define CDIM 2048
#define NPIX 196    // 14*14
#define HIN 14
#define N2 784      // 28*28
#define W2 28
#define KDIM 113
#define KC 112
#define NCLS 200
#define BN 112      // cols per block; 7*112 = 784 exact
#define NSTEP 64    // 2048/32

// ---------------- K_prep: concepts -> bf16 (padded 128 rows) + csq from rounded values ----------------
__global__ __launch_bounds__(256) void k_prep(const float* __restrict__ concepts,
                                              ushort* __restrict__ cbf,
                                              float* __restrict__ csq) {
  int k = blockIdx.x, t = threadIdx.x;
  float s = 0.f;
  for (int c = t; c < CDIM; c += 256) {
    float v = (k < KDIM) ? concepts[(size_t)k * CDIM + c] : 0.f;
    __hip_bfloat16 h = __float2bfloat16(v);
    cbf[(size_t)k * CDIM + c] = __bfloat16_as_ushort(h);
    float vb = __bfloat162float(h);
    s = fmaf(vb, vb, s);
  }
  __shared__ float r[4];
#pragma unroll
  for (int off = 32; off > 0; off >>= 1) s += __shfl_down(s, off, 64);
  if ((t & 63) == 0) r[t >> 6] = s;
  __syncthreads();
  if (t == 0) csq[k] = r[0] + r[1] + r[2] + r[3];
}

// ---------------- K_main: fused upsample + bf16 MFMA dist GEMM + softmax + logit partials ----------------
__global__ __launch_bounds__(512) void k_main(
    const float* __restrict__ x,         // [32][2048][14][14]
    const ushort* __restrict__ cbf,      // [128][2048] bf16 bits (rows >=113 zero)
    const float* __restrict__ cfcw,      // [2048]
    const float* __restrict__ csq,       // [128]
    float* __restrict__ attn_out,        // [32][113][784]
    float* __restrict__ part)            // [32][7][112]
{
  union SmemU {
    struct { ushort A[2][128][32]; ushort B[2][BN][32]; } ab;  // 30.7 KB
    float Sm[128][116];                                        // 59.4 KB
  };
  __shared__ SmemU u;
  __shared__ float cfcw_s[CDIM];
  __shared__ float red[4][BN][2];
  __shared__ float xsq[BN], proj[BN], csq_s[KDIM];

  const int tid = threadIdx.x;
  const int b = blockIdx.y, bx = blockIdx.x;
  const int n0 = bx * BN;
  const int lane = tid & 63, w = tid >> 6;     // wave w owns k-rows w*16..w*16+15
  const int lr = lane & 15, gs = lane >> 4;    // fragment coords
  // A staging: thread -> (row, 16B segment)
  const int arow = tid >> 2, aseg = tid & 3;
  // B staging: 448 threads, thread -> (channel group g, column nn)
  const bool bact = tid < 448;
  const int g = tid / BN;
  const int nn = tid - g * BN;

  // bilinear params for column n0+nn (src = 0.5*o - 0.25, edge-clamped)
  int n = n0 + nn;
  int i2 = n / W2, j2 = n - i2 * W2;
  float si = 0.5f * i2 - 0.25f;
  float sj = 0.5f * j2 - 0.25f;
  float fif = floorf(si), fjf = floorf(sj);
  int ii = (int)fif, jj = (int)fjf;
  float fi = si - fif, fj = sj - fjf;
  int ia = ii < 0 ? 0 : ii;
  int ib = (ii + 1 > 13) ? 13 : (ii + 1);
  int ja = jj < 0 ? 0 : jj;
  int jb = (jj + 1 > 13) ? 13 : (jj + 1);
  const float w00 = (1.f - fi) * (1.f - fj), w01 = (1.f - fi) * fj;
  const float w10 = fi * (1.f - fj),         w11 = fi * fj;
  const int o00 = ia * HIN + ja, o01 = ia * HIN + jb;
  const int o10 = ib * HIN + ja, o11 = ib * HIN + jb;

  for (int i = tid; i < CDIM; i += 512) cfcw_s[i] = cfcw[i];
  if (tid < KDIM) csq_s[tid] = csq[tid];

  const float* xb = x + (size_t)b * CDIM * NPIX;
  float psq = 0.f, ppj = 0.f;

  f32x4 acc[7];
#pragma unroll
  for (int t = 0; t < 7; ++t) acc[t] = f32x4{0.f, 0.f, 0.f, 0.f};

  // pipelined K-loop: stage s+1 (loads -> MFMA on s -> writes), one barrier/step
  for (int s = -1; s < NSTEP; ++s) {
    const bool more = (s + 1) < NSTEP;
    const int c0n = (s + 1) * 32;
    uint4 a_st;
    float bv[8];
    if (more) {
      a_st = *(const uint4*)(cbf + (size_t)arow * CDIM + c0n + aseg * 8);
      if (bact) {
#pragma unroll
        for (int j = 0; j < 8; ++j) {
          const float* xr = xb + (size_t)(c0n + g * 8 + j) * NPIX;
          bv[j] = w00 * xr[o00] + w01 * xr[o01] + w10 * xr[o10] + w11 * xr[o11];
        }
      }
    }
    if (s >= 0) {
      const int cb = s & 1;
      short8 af = *(const short8*)&u.ab.A[cb][w * 16 + lr][gs * 8];
#pragma unroll
      for (int t = 0; t < 7; ++t) {
        short8 bfr = *(const short8*)&u.ab.B[cb][t * 16 + lr][gs * 8];
        acc[t] = __builtin_amdgcn_mfma_f32_16x16x32_bf16(af, bfr, acc[t], 0, 0, 0);
      }
    }
    if (more) {
      const int nb = (s + 1) & 1;
      *(uint4*)&u.ab.A[nb][arow][aseg * 8] = a_st;
      if (bact) {
        uint us[4];
#pragma unroll
        for (int p = 0; p < 4; ++p) {
          __hip_bfloat16 h0 = __float2bfloat16(bv[p * 2]);
          __hip_bfloat16 h1 = __float2bfloat16(bv[p * 2 + 1]);
          float v0 = __bfloat162float(h0), v1 = __bfloat162float(h1);
          psq = fmaf(v0, v0, psq);
          psq = fmaf(v1, v1, psq);
          ppj = fmaf(v0, cfcw_s[c0n + g * 8 + p * 2], ppj);
          ppj = fmaf(v1, cfcw_s[c0n + g * 8 + p * 2 + 1], ppj);
          us[p] = (uint)__bfloat16_as_ushort(h0) | ((uint)__bfloat16_as_ushort(h1) << 16);
        }
        uint4 pk; pk.x = us[0]; pk.y = us[1]; pk.z = us[2]; pk.w = us[3];
        *(uint4*)&u.ab.B[nb][nn][g * 8] = pk;
      }
    }
    __syncthreads();
  }

  // reduce x_sq / proj across the 4 channel-groups
  if (bact) { red[g][nn][0] = psq; red[g][nn][1] = ppj; }
  __syncthreads();
  if (tid < BN) {
    float sq = 0.f, pj = 0.f;
#pragma unroll
    for (int gg = 0; gg < 4; ++gg) { sq += red[gg][tid][0]; pj += red[gg][tid][1]; }
    xsq[tid] = sq; proj[tid] = pj;
  }
  __syncthreads();

  // d2 -> -dist into Sm  (C/D layout: col=lane&15, row=(lane>>4)*4+reg)
#pragma unroll
  for (int t = 0; t < 7; ++t) {
    int col = t * 16 + lr;
#pragma unroll
    for (int q = 0; q < 4; ++q) {
      int k = w * 16 + gs * 4 + q;
      if (k < KDIM) {
        float d2 = csq_s[k] + xsq[col] - 2.f * acc[t][q];
        u.Sm[k][col] = -sqrtf(fmaxf(d2, 0.f));
      }
    }
  }
  __syncthreads();

  // softmax over k per column; write attn (coalesced per k-row)
  if (tid < BN) {
    const int col = tid;
    float m = -1e30f;
    for (int k = 0; k < KDIM; ++k) m = fmaxf(m, u.Sm[k][col]);
    float sum = 0.f;
    for (int k = 0; k < KDIM; ++k) {
      float e = __expf(u.Sm[k][col] - m);
      u.Sm[k][col] = e;
      sum += e;
    }
    float rinv = 1.f / sum;
    float* op = attn_out + (size_t)b * KDIM * N2 + n0 + col;
    for (int k = 0; k < KDIM; ++k) {
      float a2 = u.Sm[k][col] * rinv;
      u.Sm[k][col] = a2;
      op[(size_t)k * N2] = a2;
    }
  }
  __syncthreads();

  // logit partials: part[b,bx,k] = sum_col attn[k,col]*proj[col]
  if (tid < KC) {
    float lg = 0.f;
    for (int c2 = 0; c2 < BN; ++c2) lg = fmaf(u.Sm[tid][c2], proj[c2], lg);
    part[((size_t)b * 7 + bx) * KC + tid] = lg;
  }
}

// ---------------- K4: reduce partials -> sigmoid -> concept_scores ----------------
__global__ void k_sig(const float* __restrict__ part, const float* __restrict__ cfcb,
                      float* __restrict__ cs_out) {
  int i = blockIdx.x * blockDim.x + threadIdx.x;
  if (i >= BDIM * KC) return;
  int b = i / KC, k = i % KC;
  float l = cfcb[0];
#pragma unroll
  for (int t = 0; t < 7; ++t) l += part[((size_t)b * 7 + t) * KC + k];
  cs_out[i] = 1.f / (1.f + __expf(-l));
}

// ---------------- K5a: tmp[b,c] = sum_k cs[b,k] * concepts[k,c] ----------------
__global__ __launch_bounds__(256) void k_tmp(
    const float* __restrict__ concepts, const float* __restrict__ cs,
    float* __restrict__ tmp) {
  __shared__ float cs_s[KC];
  const int b = blockIdx.y;
  const int c = blockIdx.x * 256 + threadIdx.x;
  if (threadIdx.x < KC) cs_s[threadIdx.x] = cs[b * KC + threadIdx.x];
  __syncthreads();
  float a = 0.f;
#pragma unroll 8
  for (int k = 0; k < KC; ++k) a = fmaf(cs_s[k], concepts[(size_t)k * CDIM + c], a);
  tmp[(size_t)b * CDIM + c] = a;
}

// ---------------- K5b: preds[b,cls] = tmp[b,:].labw[cls,:] + labb ----------------
__global__ __launch_bounds__(256) void k_pred2(
    const float* __restrict__ labw, const float* __restrict__ labb,
    const float* __restrict__ tmp, float* __restrict__ preds) {
  const int w = blockIdx.x * 4 + (threadIdx.x >> 6);
  const int lane = threadIdx.x & 63;
  const int b = w / NCLS, cls = w % NCLS;
  if (b >= BDIM) return;
  const float* tr = tmp + (size_t)b * CDIM;
  const float* wr = labw + (size_t)cls * CDIM;
  float a = 0.f;
#pragma unroll
  for (int c0 = 0; c0 < CDIM; c0 += 256) {
    float4 t = *(const float4*)&tr[c0 + lane * 4];
    float4 v = *(const float4*)&wr[c0 + lane * 4];
    a += t.x * v.x + t.y * v.y + t.z * v.z + t.w * v.w;
  }
#pragma unroll
  for (int off = 32; off > 0; off >>= 1) a += __shfl_down(a, off, 64);
  if (lane == 0) preds[b * NCLS + cls] = a + labb[cls];
}

extern "C" void kernel_launch(void* const* d_in, const int* in_sizes, int n_in,
                              void* d_out, int out_size, void* d_ws, size_t ws_size,
                              hipStream_t stream) {
  const float* x        = (const float*)d_in[0];
  const float* concepts = (const float*)d_in[1];
  const float* cfcw     = (const float*)d_in[2];
  const float* cfcb     = (const float*)d_in[3];
  const float* labw     = (const float*)d_in[4];
  const float* labb     = (const float*)d_in[5];

  float* out    = (float*)d_out;
  float* sm_out = out;                                  // [32][113][784]
  float* cs_out = out + (size_t)BDIM * KDIM * N2;       // [32][112]
  float* pr_out = cs_out + (size_t)BDIM * KC;           // [32][200]

  float* csq  = (float*)d_ws;                        // 128 floats
  float* part = csq + 128;                           // 32*7*112
  float* tmp  = part + (size_t)BDIM * 7 * KC;        // 32*2048
  ushort* cbf = (ushort*)(tmp + (size_t)BDIM * CDIM); // 128*2048 bf16 bits (16B-aligned)

  k_prep<<<dim3(128), dim3(256), 0, stream>>>(concepts, cbf, csq);
  k_main<<<dim3(7, BDIM), dim3(512), 0, stream>>>(x, cbf, cfcw, csq, sm_out, part);
  k_sig <<<dim3((BDIM * KC + 255) / 256), dim3(256), 0, stream>>>(part, cfcb, cs_out);
  k_tmp <<<dim3(CDIM / 256, BDIM), dim3(256), 0, stream>>>(concepts, cs_out, tmp);
  k_pred2<<<dim3((BDIM * NCLS + 3) / 4), dim3(256), 0, stream>>>(labw, labb, tmp, pr_out);
}

// Round 4
// 148.667 us; speedup vs baseline: 6.5598x; 1.4196x over previous
//
#include <hip/hip_runtime.h>
#include <hip/hip_bf16.h>
#include <cstdint>

typedef __attribute__((ext_vector_type(8))) short short8;
typedef __attribute__((ext_vector_type(4))) float f32x4;

#define BDIM 32
#define CDIM 2048
#define NPIX 196    // 14*14
#define HIN 14
#define N2 784      // 28*28
#define W2 28
#define KDIM 113
#define KC 112
#define NCLS 200
#define BN 112      // cols per block; 7*112 = 784 exact
#define NSTEP 64    // 2048/32
#define SMLD 117    // Sm row stride (conflict-free: 117 mod 32 = 21, gcd(21,32)=1)

// ---------------- K_prep: concepts -> bf16, PRE-PERMUTED to LDS fragment order, + csq ----------------
// Layout: for step s (32 ch), tile t (16 k-rows), gs (4 ch-groups of 8), lr (16 rows):
//   cbf[ (((s*8+t)*4+gs)*16 + lr)*8 + j ]  = bf16(concepts[k = t*16+lr][c = s*32+gs*8+j])
// One step = 4096 ushorts = 8192 B; a 512-thread block stages it as 512 coalesced uint4.
__global__ __launch_bounds__(256) void k_prep(const float* __restrict__ concepts,
                                              ushort* __restrict__ cbf,
                                              float* __restrict__ csq) {
  int k = blockIdx.x, t = threadIdx.x;
  const int kt = k >> 4, lr = k & 15;
  float s = 0.f;
  for (int c = t; c < CDIM; c += 256) {
    float v = (k < KDIM) ? concepts[(size_t)k * CDIM + c] : 0.f;
    __hip_bfloat16 h = __float2bfloat16(v);
    int st = c >> 5, gs = (c >> 3) & 3, j = c & 7;
    cbf[((((size_t)st * 8 + kt) * 4 + gs) * 16 + lr) * 8 + j] = __bfloat16_as_ushort(h);
    float vb = __bfloat162float(h);
    s = fmaf(vb, vb, s);
  }
  __shared__ float r[4];
#pragma unroll
  for (int off = 32; off > 0; off >>= 1) s += __shfl_down(s, off, 64);
  if ((t & 63) == 0) r[t >> 6] = s;
  __syncthreads();
  if (t == 0) csq[k] = r[0] + r[1] + r[2] + r[3];
}

// ---------------- K_main: fused upsample + bf16 MFMA dist GEMM + softmax + logit partials ----------------
__global__ __launch_bounds__(512) void k_main(
    const float* __restrict__ x,         // [32][2048][14][14]
    const ushort* __restrict__ cbf,      // pre-permuted bf16 concepts
    const float* __restrict__ cfcw,      // [2048]
    const float* __restrict__ csq,       // [128]
    float* __restrict__ attn_out,        // [32][113][784]
    float* __restrict__ part)            // [32][7][112]
{
  union SmemU {
    struct { ushort A[2][4096]; ushort B[2][3584]; } ab;  // 30.7 KB, fragment-major
    float Sm[128][SMLD];                                  // 59.9 KB
  };
  __shared__ SmemU u;
  __shared__ float cfcw_s[CDIM];
  __shared__ float red[4][BN][2];
  __shared__ float xsq[BN], proj[BN], csq_s[KDIM];

  const int tid = threadIdx.x;
  const int b = blockIdx.y, bx = blockIdx.x;
  const int n0 = bx * BN;
  const int lane = tid & 63, w = tid >> 6;     // wave w owns k-rows w*16..w*16+15
  const int lr = lane & 15, gs = lane >> 4;    // fragment coords
  // B staging: 448 threads, thread -> (channel group g, column nn)
  const bool bact = tid < 448;
  const int g = tid / BN;
  const int nn = tid - g * BN;
  // B LDS write slot for (nn, g): tile nn>>4, row nn&15
  const int boff = (((nn >> 4) * 4 + g) * 16 + (nn & 15)) * 8;

  // bilinear params for column n0+nn (src = 0.5*o - 0.25, edge-clamped)
  int n = n0 + nn;
  int i2 = n / W2, j2 = n - i2 * W2;
  float si = 0.5f * i2 - 0.25f;
  float sj = 0.5f * j2 - 0.25f;
  float fif = floorf(si), fjf = floorf(sj);
  int ii = (int)fif, jj = (int)fjf;
  float fi = si - fif, fj = sj - fjf;
  int ia = ii < 0 ? 0 : ii;
  int ib = (ii + 1 > 13) ? 13 : (ii + 1);
  int ja = jj < 0 ? 0 : jj;
  int jb = (jj + 1 > 13) ? 13 : (jj + 1);
  const float w00 = (1.f - fi) * (1.f - fj), w01 = (1.f - fi) * fj;
  const float w10 = fi * (1.f - fj),         w11 = fi * fj;
  const int o00 = ia * HIN + ja, o01 = ia * HIN + jb;
  const int o10 = ib * HIN + ja, o11 = ib * HIN + jb;

  for (int i = tid; i < CDIM; i += 512) cfcw_s[i] = cfcw[i];
  if (tid < KDIM) csq_s[tid] = csq[tid];

  const float* xb = x + (size_t)b * CDIM * NPIX;
  float psq = 0.f, ppj = 0.f;

  f32x4 acc[7];
#pragma unroll
  for (int t = 0; t < 7; ++t) acc[t] = f32x4{0.f, 0.f, 0.f, 0.f};

  // pipelined K-loop: stage s+1 (loads -> MFMA on s -> writes), one barrier/step
  for (int s = -1; s < NSTEP; ++s) {
    const bool more = (s + 1) < NSTEP;
    uint4 a_st;
    float bv[8];
    if (more) {
      const int c0n = (s + 1) * 32;
      // A: one coalesced uint4 per thread from pre-permuted cbf
      a_st = *(const uint4*)(cbf + (size_t)(s + 1) * 4096 + tid * 8);
      if (bact) {
#pragma unroll
        for (int j = 0; j < 8; ++j) {
          const float* xr = xb + (size_t)(c0n + g * 8 + j) * NPIX;
          bv[j] = w00 * xr[o00] + w01 * xr[o01] + w10 * xr[o10] + w11 * xr[o11];
        }
      }
    }
    if (s >= 0) {
      const int cb = s & 1;
      // fragment reads: base + tile*1024B + lane*16B  -> contiguous, conflict-free
      short8 af = *(const short8*)&u.ab.A[cb][w * 512 + lane * 8];
#pragma unroll
      for (int t = 0; t < 7; ++t) {
        short8 bfr = *(const short8*)&u.ab.B[cb][t * 512 + lane * 8];
        acc[t] = __builtin_amdgcn_mfma_f32_16x16x32_bf16(af, bfr, acc[t], 0, 0, 0);
      }
    }
    if (more) {
      const int nb = (s + 1) & 1;
      const int c0n = (s + 1) * 32;
      *(uint4*)&u.ab.A[nb][tid * 8] = a_st;
      if (bact) {
        uint us[4];
#pragma unroll
        for (int p = 0; p < 4; ++p) {
          __hip_bfloat16 h0 = __float2bfloat16(bv[p * 2]);
          __hip_bfloat16 h1 = __float2bfloat16(bv[p * 2 + 1]);
          float v0 = __bfloat162float(h0), v1 = __bfloat162float(h1);
          psq = fmaf(v0, v0, psq);
          psq = fmaf(v1, v1, psq);
          ppj = fmaf(v0, cfcw_s[c0n + g * 8 + p * 2], ppj);
          ppj = fmaf(v1, cfcw_s[c0n + g * 8 + p * 2 + 1], ppj);
          us[p] = (uint)__bfloat16_as_ushort(h0) | ((uint)__bfloat16_as_ushort(h1) << 16);
        }
        uint4 pk; pk.x = us[0]; pk.y = us[1]; pk.z = us[2]; pk.w = us[3];
        *(uint4*)&u.ab.B[nb][boff] = pk;
      }
    }
    __syncthreads();
  }

  // reduce x_sq / proj across the 4 channel-groups
  if (bact) { red[g][nn][0] = psq; red[g][nn][1] = ppj; }
  __syncthreads();
  if (tid < BN) {
    float sq = 0.f, pj = 0.f;
#pragma unroll
    for (int gg = 0; gg < 4; ++gg) { sq += red[gg][tid][0]; pj += red[gg][tid][1]; }
    xsq[tid] = sq; proj[tid] = pj;
  }
  __syncthreads();

  // d2 -> -dist into Sm  (C/D layout: col=lane&15, row=(lane>>4)*4+reg)
#pragma unroll
  for (int t = 0; t < 7; ++t) {
    int col = t * 16 + lr;
#pragma unroll
    for (int q = 0; q < 4; ++q) {
      int k = w * 16 + gs * 4 + q;
      if (k < KDIM) {
        float d2 = csq_s[k] + xsq[col] - 2.f * acc[t][q];
        u.Sm[k][col] = -sqrtf(fmaxf(d2, 0.f));
      }
    }
  }
  __syncthreads();

  // softmax over k per column; write attn (coalesced per k-row)
  if (tid < BN) {
    const int col = tid;
    float m = -1e30f;
    for (int k = 0; k < KDIM; ++k) m = fmaxf(m, u.Sm[k][col]);
    float sum = 0.f;
    for (int k = 0; k < KDIM; ++k) {
      float e = __expf(u.Sm[k][col] - m);
      u.Sm[k][col] = e;
      sum += e;
    }
    float rinv = 1.f / sum;
    float* op = attn_out + (size_t)b * KDIM * N2 + n0 + col;
    for (int k = 0; k < KDIM; ++k) {
      float a2 = u.Sm[k][col] * rinv;
      u.Sm[k][col] = a2;
      op[(size_t)k * N2] = a2;
    }
  }
  __syncthreads();

  // logit partials: part[b,bx,k] = sum_col attn[k,col]*proj[col]
  if (tid < KC) {
    float lg = 0.f;
    for (int c2 = 0; c2 < BN; ++c2) lg = fmaf(u.Sm[tid][c2], proj[c2], lg);
    part[((size_t)b * 7 + bx) * KC + tid] = lg;
  }
}

// ---------------- K4: reduce partials -> sigmoid -> concept_scores ----------------
__global__ void k_sig(const float* __restrict__ part, const float* __restrict__ cfcb,
                      float* __restrict__ cs_out) {
  int i = blockIdx.x * blockDim.x + threadIdx.x;
  if (i >= BDIM * KC) return;
  int b = i / KC, k = i % KC;
  float l = cfcb[0];
#pragma unroll
  for (int t = 0; t < 7; ++t) l += part[((size_t)b * 7 + t) * KC + k];
  cs_out[i] = 1.f / (1.f + __expf(-l));
}

// ---------------- K5a: tmp[b,c] = sum_k cs[b,k] * concepts[k,c] ----------------
__global__ __launch_bounds__(256) void k_tmp(
    const float* __restrict__ concepts, const float* __restrict__ cs,
    float* __restrict__ tmp) {
  __shared__ float cs_s[KC];
  const int b = blockIdx.y;
  const int c = blockIdx.x * 256 + threadIdx.x;
  if (threadIdx.x < KC) cs_s[threadIdx.x] = cs[b * KC + threadIdx.x];
  __syncthreads();
  float a = 0.f;
#pragma unroll 8
  for (int k = 0; k < KC; ++k) a = fmaf(cs_s[k], concepts[(size_t)k * CDIM + c], a);
  tmp[(size_t)b * CDIM + c] = a;
}

// ---------------- K5b: preds[b,cls] = tmp[b,:].labw[cls,:] + labb ----------------
__global__ __launch_bounds__(256) void k_pred2(
    const float* __restrict__ labw, const float* __restrict__ labb,
    const float* __restrict__ tmp, float* __restrict__ preds) {
  const int w = blockIdx.x * 4 + (threadIdx.x >> 6);
  const int lane = threadIdx.x & 63;
  const int b = w / NCLS, cls = w % NCLS;
  if (b >= BDIM) return;
  const float* tr = tmp + (size_t)b * CDIM;
  const float* wr = labw + (size_t)cls * CDIM;
  float a = 0.f;
#pragma unroll
  for (int c0 = 0; c0 < CDIM; c0 += 256) {
    float4 t = *(const float4*)&tr[c0 + lane * 4];
    float4 v = *(const float4*)&wr[c0 + lane * 4];
    a += t.x * v.x + t.y * v.y + t.z * v.z + t.w * v.w;
  }
#pragma unroll
  for (int off = 32; off > 0; off >>= 1) a += __shfl_down(a, off, 64);
  if (lane == 0) preds[b * NCLS + cls] = a + labb[cls];
}

extern "C" void kernel_launch(void* const* d_in, const int* in_sizes, int n_in,
                              void* d_out, int out_size, void* d_ws, size_t ws_size,
                              hipStream_t stream) {
  const float* x        = (const float*)d_in[0];
  const float* concepts = (const float*)d_in[1];
  const float* cfcw     = (const float*)d_in[2];
  const float* cfcb     = (const float*)d_in[3];
  const float* labw     = (const float*)d_in[4];
  const float* labb     = (const float*)d_in[5];

  float* out    = (float*)d_out;
  float* sm_out = out;                                  // [32][113][784]
  float* cs_out = out + (size_t)BDIM * KDIM * N2;       // [32][112]
  float* pr_out = cs_out + (size_t)BDIM * KC;           // [32][200]

  float* csq  = (float*)d_ws;                        // 128 floats
  float* part = csq + 128;                           // 32*7*112
  float* tmp  = part + (size_t)BDIM * 7 * KC;        // 32*2048
  ushort* cbf = (ushort*)(tmp + (size_t)BDIM * CDIM); // 128*2048 bf16, pre-permuted

  k_prep<<<dim3(128), dim3(256), 0, stream>>>(concepts, cbf, csq);
  k_main<<<dim3(7, BDIM), dim3(512), 0, stream>>>(x, cbf, cfcw, csq, sm_out, part);
  k_sig <<<dim3((BDIM * KC + 255) / 256), dim3(256), 0, stream>>>(part, cfcb, cs_out);
  k_tmp <<<dim3(CDIM / 256, BDIM), dim3(256), 0, stream>>>(concepts, cs_out, tmp);
  k_pred2<<<dim3((BDIM * NCLS + 3) / 4), dim3(256), 0, stream>>>(labw, labb, tmp, pr_out);
}

// Round 5
// 142.992 us; speedup vs baseline: 6.8202x; 1.0397x over previous
//
#include <hip/hip_runtime.h>
#include <hip/hip_bf16.h>
#include <cstdint>

typedef __attribute__((ext_vector_type(8))) short short8;
typedef __attribute__((ext_vector_type(4))) float f32x4;

#define BDIM 32
#define CDIM 2048
#define NPIX 196    // 14*14
#define HIN 14
#define N2 784      // 28*28
#define W2 28
#define KDIM 113
#define KC 112
#define NCLS 200
#define BN 112      // cols per block; 7*112 = 784 exact
#define NSTEP 64    // 2048/32
#define SMLD 117    // Sm row stride (conflict-free)
#define PSTR 36     // k_xe transposed plane stride (16B-aligned, gs groups 8 banks apart)

// ---------------- K_prep: concepts -> bf16, PRE-PERMUTED to LDS fragment order, + csq ----------------
__global__ __launch_bounds__(256) void k_prep(const float* __restrict__ concepts,
                                              ushort* __restrict__ cbf,
                                              float* __restrict__ csq) {
  int k = blockIdx.x, t = threadIdx.x;
  const int kt = k >> 4, lr = k & 15;
  float s = 0.f;
  for (int c = t; c < CDIM; c += 256) {
    float v = (k < KDIM) ? concepts[(size_t)k * CDIM + c] : 0.f;
    __hip_bfloat16 h = __float2bfloat16(v);
    int st = c >> 5, gs = (c >> 3) & 3, j = c & 7;
    cbf[((((size_t)st * 8 + kt) * 4 + gs) * 16 + lr) * 8 + j] = __bfloat16_as_ushort(h);
    float vb = __bfloat162float(h);
    s = fmaf(vb, vb, s);
  }
  __shared__ float r[4];
#pragma unroll
  for (int off = 32; off > 0; off >>= 1) s += __shfl_down(s, off, 64);
  if ((t & 63) == 0) r[t >> 6] = s;
  __syncthreads();
  if (t == 0) csq[k] = r[0] + r[1] + r[2] + r[3];
}

// ---------------- K_xe: upsample once -> bf16 xep in exact LDS fragment image ----------------
// xep[(b*7+bx)*64 + s][3584]: slot sl = t*64+gs*16+lr (uint4 granules), col nn=t*16+lr,
// channels c = s*32 + gs*8 + 0..7.  Block = (s, b), 512 threads.
__global__ __launch_bounds__(512) void k_xe(const float* __restrict__ x,
                                            ushort* __restrict__ xep) {
  __shared__ float P[NPIX][PSTR];  // transposed planes: P[pix][ch]
  const int s = blockIdx.x, b = blockIdx.y;
  const int tid = threadIdx.x;
  const float* src = x + ((size_t)b * CDIM + s * 32) * NPIX;
  {
    const int cl = tid >> 4, p0 = tid & 15;
#pragma unroll
    for (int k = 0; k < 13; ++k) {
      int p = p0 + (k << 4);
      if (p < NPIX) P[p][cl] = src[cl * NPIX + p];
    }
  }
  __syncthreads();
  if (tid >= 448) return;
  const int t = tid >> 6, gs = (tid >> 4) & 3, lr = tid & 15;
  const int nn = t * 16 + lr;
  const int gs8 = gs * 8;
  for (int bx = 0; bx < 7; ++bx) {
    const int n = bx * BN + nn;
    int i2 = n / W2, j2 = n - i2 * W2;
    float si = 0.5f * i2 - 0.25f;
    float sj = 0.5f * j2 - 0.25f;
    float fif = floorf(si), fjf = floorf(sj);
    int ii = (int)fif, jj = (int)fjf;
    float fi = si - fif, fj = sj - fjf;
    int ia = ii < 0 ? 0 : ii;
    int ib = (ii + 1 > 13) ? 13 : (ii + 1);
    int ja = jj < 0 ? 0 : jj;
    int jb = (jj + 1 > 13) ? 13 : (jj + 1);
    const float w00 = (1.f - fi) * (1.f - fj), w01 = (1.f - fi) * fj;
    const float w10 = fi * (1.f - fj),         w11 = fi * fj;
    const int o00 = ia * HIN + ja, o01 = ia * HIN + jb;
    const int o10 = ib * HIN + ja, o11 = ib * HIN + jb;
    float T00[8], T01[8], T10[8], T11[8];
    *(float4*)&T00[0] = *(const float4*)&P[o00][gs8];
    *(float4*)&T00[4] = *(const float4*)&P[o00][gs8 + 4];
    *(float4*)&T01[0] = *(const float4*)&P[o01][gs8];
    *(float4*)&T01[4] = *(const float4*)&P[o01][gs8 + 4];
    *(float4*)&T10[0] = *(const float4*)&P[o10][gs8];
    *(float4*)&T10[4] = *(const float4*)&P[o10][gs8 + 4];
    *(float4*)&T11[0] = *(const float4*)&P[o11][gs8];
    *(float4*)&T11[4] = *(const float4*)&P[o11][gs8 + 4];
    uint us[4];
#pragma unroll
    for (int p = 0; p < 4; ++p) {
      float v0 = w00 * T00[2 * p] + w01 * T01[2 * p] + w10 * T10[2 * p] + w11 * T11[2 * p];
      float v1 = w00 * T00[2 * p + 1] + w01 * T01[2 * p + 1] + w10 * T10[2 * p + 1] + w11 * T11[2 * p + 1];
      us[p] = (uint)__bfloat16_as_ushort(__float2bfloat16(v0)) |
              ((uint)__bfloat16_as_ushort(__float2bfloat16(v1)) << 16);
    }
    uint4 pk; pk.x = us[0]; pk.y = us[1]; pk.z = us[2]; pk.w = us[3];
    *(uint4*)&xep[(((size_t)(b * 7 + bx) * 64 + s) * 3584) + (size_t)tid * 8] = pk;
  }
}

// ---------------- K_gemm (fast path): pure MFMA GEMM + softmax + logit partials ----------------
__global__ __launch_bounds__(512) void k_gemm(
    const ushort* __restrict__ xep,      // pre-permuted bf16 xe
    const ushort* __restrict__ cbf,      // pre-permuted bf16 concepts
    const float* __restrict__ cfcw,      // [2048]
    const float* __restrict__ csq,       // [128]
    float* __restrict__ attn_out,        // [32][113][784]
    float* __restrict__ part)            // [32][7][112]
{
  union SmemU {
    struct { ushort A[2][4096]; ushort B[2][3584]; } ab;
    float Sm[128][SMLD];
  };
  __shared__ SmemU u;
  __shared__ float cfcw_s[CDIM];
  __shared__ float red[4][BN][2];
  __shared__ float xsq[BN], proj[BN], csq_s[KDIM];

  const int tid = threadIdx.x;
  const int b = blockIdx.y, bx = blockIdx.x;
  const int n0 = bx * BN;
  const int lane = tid & 63, w = tid >> 6;
  const int lr = lane & 15, gs = lane >> 4;
  const bool bact = tid < 448;
  const int g = (tid >> 4) & 3;                    // staged channel group
  const int nn = (tid >> 6) * 16 + (tid & 15);     // staged column

  for (int i = tid; i < CDIM; i += 512) cfcw_s[i] = cfcw[i];
  if (tid < KDIM) csq_s[tid] = csq[tid];

  const ushort* xb = xep + (size_t)(b * 7 + bx) * 64 * 3584;
  float psq = 0.f, ppj = 0.f;

  f32x4 acc[7];
#pragma unroll
  for (int t = 0; t < 7; ++t) acc[t] = f32x4{0.f, 0.f, 0.f, 0.f};

  for (int s = -1; s < NSTEP; ++s) {
    const bool more = (s + 1) < NSTEP;
    uint4 a_st, b_st;
    if (more) {
      a_st = *(const uint4*)(cbf + (size_t)(s + 1) * 4096 + tid * 8);
      if (bact) b_st = *(const uint4*)(xb + (size_t)(s + 1) * 3584 + tid * 8);
    }
    if (s >= 0) {
      const int cb = s & 1;
      short8 af = *(const short8*)&u.ab.A[cb][w * 512 + lane * 8];
#pragma unroll
      for (int t = 0; t < 7; ++t) {
        short8 bfr = *(const short8*)&u.ab.B[cb][t * 512 + lane * 8];
        acc[t] = __builtin_amdgcn_mfma_f32_16x16x32_bf16(af, bfr, acc[t], 0, 0, 0);
      }
    }
    if (more) {
      const int nb = (s + 1) & 1;
      const int c0n = (s + 1) * 32;
      *(uint4*)&u.ab.A[nb][tid * 8] = a_st;
      if (bact) {
        *(uint4*)&u.ab.B[nb][tid * 8] = b_st;
        uint uu[4] = {b_st.x, b_st.y, b_st.z, b_st.w};
#pragma unroll
        for (int p = 0; p < 4; ++p) {
          float v0 = __uint_as_float(uu[p] << 16);
          float v1 = __uint_as_float(uu[p] & 0xffff0000u);
          psq = fmaf(v0, v0, psq);
          psq = fmaf(v1, v1, psq);
          ppj = fmaf(v0, cfcw_s[c0n + g * 8 + p * 2], ppj);
          ppj = fmaf(v1, cfcw_s[c0n + g * 8 + p * 2 + 1], ppj);
        }
      }
    }
    __syncthreads();
  }

  if (bact) { red[g][nn][0] = psq; red[g][nn][1] = ppj; }
  __syncthreads();
  if (tid < BN) {
    float sq = 0.f, pj = 0.f;
#pragma unroll
    for (int gg = 0; gg < 4; ++gg) { sq += red[gg][tid][0]; pj += red[gg][tid][1]; }
    xsq[tid] = sq; proj[tid] = pj;
  }
  __syncthreads();

#pragma unroll
  for (int t = 0; t < 7; ++t) {
    int col = t * 16 + lr;
#pragma unroll
    for (int q = 0; q < 4; ++q) {
      int k = w * 16 + gs * 4 + q;
      if (k < KDIM) {
        float d2 = csq_s[k] + xsq[col] - 2.f * acc[t][q];
        u.Sm[k][col] = -sqrtf(fmaxf(d2, 0.f));
      }
    }
  }
  __syncthreads();

  if (tid < BN) {
    const int col = tid;
    float m = -1e30f;
    for (int k = 0; k < KDIM; ++k) m = fmaxf(m, u.Sm[k][col]);
    float sum = 0.f;
    for (int k = 0; k < KDIM; ++k) {
      float e = __expf(u.Sm[k][col] - m);
      u.Sm[k][col] = e;
      sum += e;
    }
    float rinv = 1.f / sum;
    float* op = attn_out + (size_t)b * KDIM * N2 + n0 + col;
    for (int k = 0; k < KDIM; ++k) {
      float a2 = u.Sm[k][col] * rinv;
      u.Sm[k][col] = a2;
      op[(size_t)k * N2] = a2;
    }
  }
  __syncthreads();

  if (tid < KC) {
    float lg = 0.f;
    for (int c2 = 0; c2 < BN; ++c2) lg = fmaf(u.Sm[tid][c2], proj[c2], lg);
    part[((size_t)b * 7 + bx) * KC + tid] = lg;
  }
}

// ---------------- K_main fallback (round-4, used if ws too small) ----------------
__global__ __launch_bounds__(512) void k_main_fb(
    const float* __restrict__ x, const ushort* __restrict__ cbf,
    const float* __restrict__ cfcw, const float* __restrict__ csq,
    float* __restrict__ attn_out, float* __restrict__ part)
{
  union SmemU {
    struct { ushort A[2][4096]; ushort B[2][3584]; } ab;
    float Sm[128][SMLD];
  };
  __shared__ SmemU u;
  __shared__ float cfcw_s[CDIM];
  __shared__ float red[4][BN][2];
  __shared__ float xsq[BN], proj[BN], csq_s[KDIM];

  const int tid = threadIdx.x;
  const int b = blockIdx.y, bx = blockIdx.x;
  const int n0 = bx * BN;
  const int lane = tid & 63, w = tid >> 6;
  const int lr = lane & 15, gs = lane >> 4;
  const bool bact = tid < 448;
  const int g = tid / BN;
  const int nn = tid - g * BN;
  const int boff = (((nn >> 4) * 4 + g) * 16 + (nn & 15)) * 8;

  int n = n0 + nn;
  int i2 = n / W2, j2 = n - i2 * W2;
  float si = 0.5f * i2 - 0.25f;
  float sj = 0.5f * j2 - 0.25f;
  float fif = floorf(si), fjf = floorf(sj);
  int ii = (int)fif, jj = (int)fjf;
  float fi = si - fif, fj = sj - fjf;
  int ia = ii < 0 ? 0 : ii;
  int ib = (ii + 1 > 13) ? 13 : (ii + 1);
  int ja = jj < 0 ? 0 : jj;
  int jb = (jj + 1 > 13) ? 13 : (jj + 1);
  const float w00 = (1.f - fi) * (1.f - fj), w01 = (1.f - fi) * fj;
  const float w10 = fi * (1.f - fj),         w11 = fi * fj;
  const int o00 = ia * HIN + ja, o01 = ia * HIN + jb;
  const int o10 = ib * HIN + ja, o11 = ib * HIN + jb;

  for (int i = tid; i < CDIM; i += 512) cfcw_s[i] = cfcw[i];
  if (tid < KDIM) csq_s[tid] = csq[tid];

  const float* xb = x + (size_t)b * CDIM * NPIX;
  float psq = 0.f, ppj = 0.f;

  f32x4 acc[7];
#pragma unroll
  for (int t = 0; t < 7; ++t) acc[t] = f32x4{0.f, 0.f, 0.f, 0.f};

  for (int s = -1; s < NSTEP; ++s) {
    const bool more = (s + 1) < NSTEP;
    uint4 a_st;
    float bv[8];
    if (more) {
      const int c0n = (s + 1) * 32;
      a_st = *(const uint4*)(cbf + (size_t)(s + 1) * 4096 + tid * 8);
      if (bact) {
#pragma unroll
        for (int j = 0; j < 8; ++j) {
          const float* xr = xb + (size_t)(c0n + g * 8 + j) * NPIX;
          bv[j] = w00 * xr[o00] + w01 * xr[o01] + w10 * xr[o10] + w11 * xr[o11];
        }
      }
    }
    if (s >= 0) {
      const int cb = s & 1;
      short8 af = *(const short8*)&u.ab.A[cb][w * 512 + lane * 8];
#pragma unroll
      for (int t = 0; t < 7; ++t) {
        short8 bfr = *(const short8*)&u.ab.B[cb][t * 512 + lane * 8];
        acc[t] = __builtin_amdgcn_mfma_f32_16x16x32_bf16(af, bfr, acc[t], 0, 0, 0);
      }
    }
    if (more) {
      const int nb = (s + 1) & 1;
      const int c0n = (s + 1) * 32;
      *(uint4*)&u.ab.A[nb][tid * 8] = a_st;
      if (bact) {
        uint us[4];
#pragma unroll
        for (int p = 0; p < 4; ++p) {
          __hip_bfloat16 h0 = __float2bfloat16(bv[p * 2]);
          __hip_bfloat16 h1 = __float2bfloat16(bv[p * 2 + 1]);
          float v0 = __bfloat162float(h0), v1 = __bfloat162float(h1);
          psq = fmaf(v0, v0, psq);
          psq = fmaf(v1, v1, psq);
          ppj = fmaf(v0, cfcw_s[c0n + g * 8 + p * 2], ppj);
          ppj = fmaf(v1, cfcw_s[c0n + g * 8 + p * 2 + 1], ppj);
          us[p] = (uint)__bfloat16_as_ushort(h0) | ((uint)__bfloat16_as_ushort(h1) << 16);
        }
        uint4 pk; pk.x = us[0]; pk.y = us[1]; pk.z = us[2]; pk.w = us[3];
        *(uint4*)&u.ab.B[nb][boff] = pk;
      }
    }
    __syncthreads();
  }

  if (bact) { red[g][nn][0] = psq; red[g][nn][1] = ppj; }
  __syncthreads();
  if (tid < BN) {
    float sq = 0.f, pj = 0.f;
#pragma unroll
    for (int gg = 0; gg < 4; ++gg) { sq += red[gg][tid][0]; pj += red[gg][tid][1]; }
    xsq[tid] = sq; proj[tid] = pj;
  }
  __syncthreads();

#pragma unroll
  for (int t = 0; t < 7; ++t) {
    int col = t * 16 + lr;
#pragma unroll
    for (int q = 0; q < 4; ++q) {
      int k = w * 16 + gs * 4 + q;
      if (k < KDIM) {
        float d2 = csq_s[k] + xsq[col] - 2.f * acc[t][q];
        u.Sm[k][col] = -sqrtf(fmaxf(d2, 0.f));
      }
    }
  }
  __syncthreads();

  if (tid < BN) {
    const int col = tid;
    float m = -1e30f;
    for (int k = 0; k < KDIM; ++k) m = fmaxf(m, u.Sm[k][col]);
    float sum = 0.f;
    for (int k = 0; k < KDIM; ++k) {
      float e = __expf(u.Sm[k][col] - m);
      u.Sm[k][col] = e;
      sum += e;
    }
    float rinv = 1.f / sum;
    float* op = attn_out + (size_t)b * KDIM * N2 + n0 + col;
    for (int k = 0; k < KDIM; ++k) {
      float a2 = u.Sm[k][col] * rinv;
      u.Sm[k][col] = a2;
      op[(size_t)k * N2] = a2;
    }
  }
  __syncthreads();

  if (tid < KC) {
    float lg = 0.f;
    for (int c2 = 0; c2 < BN; ++c2) lg = fmaf(u.Sm[tid][c2], proj[c2], lg);
    part[((size_t)b * 7 + bx) * KC + tid] = lg;
  }
}

// ---------------- K4: reduce partials -> sigmoid -> concept_scores ----------------
__global__ void k_sig(const float* __restrict__ part, const float* __restrict__ cfcb,
                      float* __restrict__ cs_out) {
  int i = blockIdx.x * blockDim.x + threadIdx.x;
  if (i >= BDIM * KC) return;
  int b = i / KC, k = i % KC;
  float l = cfcb[0];
#pragma unroll
  for (int t = 0; t < 7; ++t) l += part[((size_t)b * 7 + t) * KC + k];
  cs_out[i] = 1.f / (1.f + __expf(-l));
}

// ---------------- K5a: tmp[b,c] = sum_k cs[b,k] * concepts[k,c] ----------------
__global__ __launch_bounds__(256) void k_tmp(
    const float* __restrict__ concepts, const float* __restrict__ cs,
    float* __restrict__ tmp) {
  __shared__ float cs_s[KC];
  const int b = blockIdx.y;
  const int c = blockIdx.x * 256 + threadIdx.x;
  if (threadIdx.x < KC) cs_s[threadIdx.x] = cs[b * KC + threadIdx.x];
  __syncthreads();
  float a = 0.f;
#pragma unroll 8
  for (int k = 0; k < KC; ++k) a = fmaf(cs_s[k], concepts[(size_t)k * CDIM + c], a);
  tmp[(size_t)b * CDIM + c] = a;
}

// ---------------- K5b: preds[b,cls] = tmp[b,:].labw[cls,:] + labb ----------------
__global__ __launch_bounds__(256) void k_pred2(
    const float* __restrict__ labw, const float* __restrict__ labb,
    const float* __restrict__ tmp, float* __restrict__ preds) {
  const int w = blockIdx.x * 4 + (threadIdx.x >> 6);
  const int lane = threadIdx.x & 63;
  const int b = w / NCLS, cls = w % NCLS;
  if (b >= BDIM) return;
  const float* tr = tmp + (size_t)b * CDIM;
  const float* wr = labw + (size_t)cls * CDIM;
  float a = 0.f;
#pragma unroll
  for (int c0 = 0; c0 < CDIM; c0 += 256) {
    float4 t = *(const float4*)&tr[c0 + lane * 4];
    float4 v = *(const float4*)&wr[c0 + lane * 4];
    a += t.x * v.x + t.y * v.y + t.z * v.z + t.w * v.w;
  }
#pragma unroll
  for (int off = 32; off > 0; off >>= 1) a += __shfl_down(a, off, 64);
  if (lane == 0) preds[b * NCLS + cls] = a + labb[cls];
}

extern "C" void kernel_launch(void* const* d_in, const int* in_sizes, int n_in,
                              void* d_out, int out_size, void* d_ws, size_t ws_size,
                              hipStream_t stream) {
  const float* x        = (const float*)d_in[0];
  const float* concepts = (const float*)d_in[1];
  const float* cfcw     = (const float*)d_in[2];
  const float* cfcb     = (const float*)d_in[3];
  const float* labw     = (const float*)d_in[4];
  const float* labb     = (const float*)d_in[5];

  float* out    = (float*)d_out;
  float* sm_out = out;                                  // [32][113][784]
  float* cs_out = out + (size_t)BDIM * KDIM * N2;       // [32][112]
  float* pr_out = cs_out + (size_t)BDIM * KC;           // [32][200]

  char* ws = (char*)d_ws;
  float*  csq  = (float*)(ws + 0);         // 128 f32          -> 512 B
  float*  part = (float*)(ws + 512);       // 32*7*112 f32     -> 100,352 B
  float*  tmp  = (float*)(ws + 100864);    // 32*2048 f32      -> 262,144 B
  ushort* cbf  = (ushort*)(ws + 363008);   // 128*2048 bf16    -> 524,288 B
  ushort* xep  = (ushort*)(ws + 887296);   // 32*7*64*3584 bf16 -> 102,760,448 B
  const size_t need_fast = 887296 + (size_t)BDIM * 7 * 64 * 3584 * 2;

  k_prep<<<dim3(128), dim3(256), 0, stream>>>(concepts, cbf, csq);
  if (ws_size >= need_fast) {
    k_xe  <<<dim3(64, BDIM), dim3(512), 0, stream>>>(x, xep);
    k_gemm<<<dim3(7, BDIM), dim3(512), 0, stream>>>(xep, cbf, cfcw, csq, sm_out, part);
  } else {
    k_main_fb<<<dim3(7, BDIM), dim3(512), 0, stream>>>(x, cbf, cfcw, csq, sm_out, part);
  }
  k_sig <<<dim3((BDIM * KC + 255) / 256), dim3(256), 0, stream>>>(part, cfcb, cs_out);
  k_tmp <<<dim3(CDIM / 256, BDIM), dim3(256), 0, stream>>>(concepts, cs_out, tmp);
  k_pred2<<<dim3((BDIM * NCLS + 3) / 4), dim3(256), 0, stream>>>(labw, labb, tmp, pr_out);
}